// Round 1
// 431.059 us; speedup vs baseline: 1.0617x; 1.0617x over previous
//
#include <hip/hip_runtime.h>
#include <hip/hip_bf16.h>
#include <math.h>

#define B_ROWS 1024
#define DDIM   512
#define CN     51332
#define CPAD   51456   /* 201 * 256 */
#define EPSF   1e-3f
#define SCALE  64.0f
#define NT     8       /* K-steps of 64 */

typedef unsigned short ushort_t;
typedef short bf16x8 __attribute__((ext_vector_type(8)));   // 8 bf16 (4 VGPRs)
typedef float f32x4  __attribute__((ext_vector_type(4)));   // 4 fp32 acc
typedef unsigned short us8 __attribute__((ext_vector_type(8)));
typedef unsigned short us4 __attribute__((ext_vector_type(4)));

static __device__ __forceinline__ unsigned short f2bf(float f) {
    // round-to-nearest-even fp32 -> bf16 (inputs are finite)
    unsigned int u = __float_as_uint(f);
    u += 0x7fffu + ((u >> 16) & 1u);
    return (unsigned short)(u >> 16);
}

// ---------------------------------------------------------------------------
// Pass 1: column sum-of-squares partials + bf16 cast + transpose to [CPAD, DDIM]
// float2-vectorized (2 cols/thread), 8 d-chunks of 64 rows: 2x bytes/instr and
// 2x resident waves vs the old scalar version (was latency-bound).
// Each (thread, col) writes one full 128-B line of kbT -> clean write-combining.
__global__ void colpass(const float* __restrict__ kern, ushort_t* __restrict__ kbT,
                        float* __restrict__ partials) {
    const int c2 = (blockIdx.x * 256 + threadIdx.x) * 2;
    if (c2 >= CPAD) return;
    const int d0 = blockIdx.y * 64;
    const bool valid = (c2 < CN);            // CN even -> both cols valid or neither
    float s0 = 0.f, s1 = 0.f;
    for (int d = d0; d < d0 + 64; d += 8) {
        us8 p0, p1;
#pragma unroll
        for (int j = 0; j < 8; ++j) {
            float x = 0.f, y = 0.f;
            if (valid) {
                const float2 v = *(const float2*)&kern[(size_t)(d + j) * CN + c2];
                x = v.x; y = v.y;
            }
            s0 += x * x; s1 += y * y;
            p0[j] = f2bf(x); p1[j] = f2bf(y);
        }
        *(us8*)&kbT[(size_t)c2 * DDIM + d]       = p0;
        *(us8*)&kbT[(size_t)(c2 + 1) * DDIM + d] = p1;
    }
    partials[(size_t)blockIdx.y * CPAD + c2]     = s0;
    partials[(size_t)blockIdx.y * CPAD + c2 + 1] = s1;
}

__global__ void finnorm(const float* __restrict__ partials, float* __restrict__ inv_norm) {
    const int c = blockIdx.x * 256 + threadIdx.x;
    float s = 0.f;
#pragma unroll
    for (int k = 0; k < 8; ++k) s += partials[(size_t)k * CPAD + c];
    inv_norm[c] = 1.0f / fmaxf(sqrtf(s), 1e-5f);
}

__global__ void embcast(const float* __restrict__ emb, ushort_t* __restrict__ embb) {
    const int t = blockIdx.x * 256 + threadIdx.x;    // 4 elems/thread
    const float4 v = ((const float4*)emb)[t];
    us4 o; o[0] = f2bf(v.x); o[1] = f2bf(v.y); o[2] = f2bf(v.z); o[3] = f2bf(v.w);
    *(us4*)&embb[(size_t)t * 4] = o;
}

// ---------------------------------------------------------------------------
// 256x256 8-phase bf16 MFMA GEMM (T2+T3+T4+T5 template, plain HIP).
//   - BM=BN=256, BK=64, 8 waves (2M x 4N), per-wave output 128x64, acc[8][4].
//   - LDS 128 KiB: A[2][256][64] | B[2][256][64] bf16, double-buffered.
//   - Swizzle (both-sides rule): global_load_lds writes linearly; the global
//     SOURCE 16B-chunk is pre-swizzled (c8^r8) and ds_read XORs chunk^(row&7).
//     -> conflict-free ds_read_b128 (was 16-way in the 128x64 layout).
//   - Each phase: {ds_read subtile | stage 1 half-tile} barrier {16 MFMA} barrier.
//     vmcnt(6) ONLY at phase 3 (counted: 3 half-tiles = 6 loads stay in flight
//     across barriers). Never vmcnt(0) in the main loop.
//   - Region safety: A fully ds_read in phase 0, B-lo by phase 1 => stages into
//     the CURRENT buffer at phases 1(A-lo),2(A-hi),3(B-lo) are barrier-separated
//     from all readers; B-hi(t+1) goes to the other buffer at phase 0.
#define MFMA(d, va, vb) (d) = __builtin_amdgcn_mfma_f32_16x16x32_bf16((va), (vb), (d), 0, 0, 0)

#define STAGE16(gp, lp) __builtin_amdgcn_global_load_lds( \
    (__attribute__((address_space(1))) void*)(gp), \
    (__attribute__((address_space(3))) void*)(lp), 16, 0, 0)

// gl: per-lane global base (includes r8*DDIM + swizzled chunk); sb: LDS ushort base
#define STAGE(gl, sb, half, kstep) do { \
    const int rb_ = (half) * 128 + w * 16; \
    STAGE16((gl) + (size_t)rb_ * DDIM + (size_t)(kstep) * 64, &(sb)[rb_ * 64]); \
    STAGE16((gl) + (size_t)(rb_ + 8) * DDIM + (size_t)(kstep) * 64, &(sb)[(rb_ + 8) * 64]); \
} while (0)

__global__ __launch_bounds__(512, 2) void gemm_kernel(
        const ushort_t* __restrict__ embb, const ushort_t* __restrict__ kbT,
        const float* __restrict__ inv_norm, float* __restrict__ out) {
    __shared__ ushort_t smem[65536];    // bytes: A[2] at 0..64K, B[2] at 64K..128K

    const int tid  = threadIdx.x;
    const int lane = tid & 63;
    const int w    = tid >> 6;                 // wave 0..7
    const int wm = w >> 2, wn = w & 3;         // 2 x 4 wave grid
    const int lm = lane & 15, lq = lane >> 4;  // MFMA row-sel / quad
    const int r8 = lane >> 3, c8 = lane & 7;   // staging lane -> (row, 16B chunk)

    // bijective XCD swizzle for 804 blocks (q=100, r=4); m-fast within an XCD
    // chunk so 4 consecutive blocks share one B-panel in that XCD's L2.
    const int bid = blockIdx.x;
    const int xcd = bid & 7, loc = bid >> 3;
    const int u  = (xcd < 4) ? (xcd * 101 + loc) : (404 + (xcd - 4) * 100 + loc);
    const int m0 = (u & 3) * 256;
    const int n0 = (u >> 2) * 256;

    // per-lane staging source pointers (chunk pre-swizzled with c8^r8)
    const ushort_t* gAl = embb + (size_t)(m0 + r8) * DDIM + ((c8 ^ r8) << 3);
    const ushort_t* gBl = kbT  + (size_t)(n0 + r8) * DDIM + ((c8 ^ r8) << 3);
    // ds_read offsets: row*64 + ((chunk)^(row&7))*8, chunk = lq + 4*ksi
    const int swz = lm & 7;
    const int ca0 = ((lq    ) ^ swz) << 3;
    const int ca1 = ((lq + 4) ^ swz) << 3;
    const int offA = (wm * 128 + lm) * 64;
    const int offB = (wn * 64  + lm) * 64;

    f32x4 acc[8][4];
#pragma unroll
    for (int i = 0; i < 8; ++i)
#pragma unroll
        for (int j = 0; j < 4; ++j) acc[i][j] = (f32x4){0.f, 0.f, 0.f, 0.f};

    // prologue: all 4 half-tiles of step 0 -> buf0, 3 of step 1 -> buf1.
    // vmcnt(6): oldest 8 loads (= step 0) done, 3 half-tiles left in flight.
    STAGE(gAl, (smem        ), 0, 0); STAGE(gAl, (smem        ), 1, 0);
    STAGE(gBl, (smem + 32768), 0, 0); STAGE(gBl, (smem + 32768), 1, 0);
    STAGE(gAl, (smem + 16384), 0, 1); STAGE(gAl, (smem + 16384), 1, 1);
    STAGE(gBl, (smem + 49152), 0, 1);
    asm volatile("s_waitcnt vmcnt(6)" ::: "memory");
    __builtin_amdgcn_s_barrier();
    __builtin_amdgcn_sched_barrier(0);

    bf16x8 a[8][2], b0[2][2], b1[2][2];

    for (int t = 0; t < NT; ++t) {
        const int cur = t & 1;
        ushort_t* Sa = smem + cur * 16384;
        ushort_t* Sb = smem + 32768 + cur * 16384;
        ushort_t* Nb = smem + 32768 + (cur ^ 1) * 16384;
        const int kA = (t + 2) & 7;   // wrapped near the end: harmless restage,
        const int kB = (t + 1) & 7;   // keeps vmcnt counts uniform

        // ---- phase 0: ds-read all-A + B[j0,j1] | stage B-hi(t+1)->nxt | MFMA i0-3 x j0-1
#pragma unroll
        for (int i = 0; i < 8; ++i) {
            a[i][0] = *(const bf16x8*)&Sa[offA + i * 1024 + ca0];
            a[i][1] = *(const bf16x8*)&Sa[offA + i * 1024 + ca1];
        }
#pragma unroll
        for (int j = 0; j < 2; ++j) {
            b0[j][0] = *(const bf16x8*)&Sb[offB + j * 1024 + ca0];
            b0[j][1] = *(const bf16x8*)&Sb[offB + j * 1024 + ca1];
        }
        STAGE(gBl, Nb, 1, kB);
        __builtin_amdgcn_s_barrier();
        __builtin_amdgcn_s_setprio(1);
#pragma unroll
        for (int i = 0; i < 4; ++i)
#pragma unroll
            for (int j = 0; j < 2; ++j) {
                MFMA(acc[i][j], a[i][0], b0[j][0]);
                MFMA(acc[i][j], a[i][1], b0[j][1]);
            }
        __builtin_amdgcn_s_setprio(0);
        __builtin_amdgcn_s_barrier();
        __builtin_amdgcn_sched_barrier(0);

        // ---- phase 1: ds-read B[j2,j3] | stage A-lo(t+2)->cur | MFMA i0-3 x j2-3
#pragma unroll
        for (int j = 0; j < 2; ++j) {
            b1[j][0] = *(const bf16x8*)&Sb[offB + (j + 2) * 1024 + ca0];
            b1[j][1] = *(const bf16x8*)&Sb[offB + (j + 2) * 1024 + ca1];
        }
        STAGE(gAl, Sa, 0, kA);
        __builtin_amdgcn_s_barrier();
        __builtin_amdgcn_s_setprio(1);
#pragma unroll
        for (int i = 0; i < 4; ++i)
#pragma unroll
            for (int j = 0; j < 2; ++j) {
                MFMA(acc[i][j + 2], a[i][0], b1[j][0]);
                MFMA(acc[i][j + 2], a[i][1], b1[j][1]);
            }
        __builtin_amdgcn_s_setprio(0);
        __builtin_amdgcn_s_barrier();
        __builtin_amdgcn_sched_barrier(0);

        // ---- phase 2: stage A-hi(t+2)->cur | MFMA i4-7 x j0-1
        STAGE(gAl, Sa, 1, kA);
        __builtin_amdgcn_s_barrier();
        __builtin_amdgcn_s_setprio(1);
#pragma unroll
        for (int i = 4; i < 8; ++i)
#pragma unroll
            for (int j = 0; j < 2; ++j) {
                MFMA(acc[i][j], a[i][0], b0[j][0]);
                MFMA(acc[i][j], a[i][1], b0[j][1]);
            }
        __builtin_amdgcn_s_setprio(0);
        __builtin_amdgcn_s_barrier();
        __builtin_amdgcn_sched_barrier(0);

        // ---- phase 3: stage B-lo(t+2)->cur | MFMA i4-7 x j2-3 | counted vmcnt(6)
        STAGE(gBl, Sb, 0, kA);
        __builtin_amdgcn_s_barrier();
        __builtin_amdgcn_s_setprio(1);
#pragma unroll
        for (int i = 4; i < 8; ++i)
#pragma unroll
            for (int j = 0; j < 2; ++j) {
                MFMA(acc[i][j + 2], a[i][0], b1[j][0]);
                MFMA(acc[i][j + 2], a[i][1], b1[j][1]);
            }
        __builtin_amdgcn_s_setprio(0);
        asm volatile("s_waitcnt vmcnt(6)" ::: "memory");
        __builtin_amdgcn_s_barrier();
        __builtin_amdgcn_sched_barrier(0);
    }

    // ---- epilogue: drain DMA, then wave-private swizzled LDS staging (4 KiB/wave,
    // no barriers needed: cross-lane within one wave only) -> coalesced 16B stores.
    asm volatile("s_waitcnt vmcnt(0)" ::: "memory");
    __syncthreads();

    float invn[4];
#pragma unroll
    for (int j = 0; j < 4; ++j) {
        const int col = n0 + wn * 64 + j * 16 + lm;
        invn[j] = (col < CN) ? inv_norm[col] : 0.f;
    }
    float* Ew = (float*)smem + w * 1024;        // 16 x 64 f32, swizzled
    const int rr = lane >> 4, cc = lane & 15;
#pragma unroll
    for (int i = 0; i < 8; ++i) {
#pragma unroll
        for (int j = 0; j < 4; ++j)
#pragma unroll
            for (int r = 0; r < 4; ++r) {
                const int row = lq * 4 + r;                    // 0..15
                const int cs  = ((j * 16 + lm) + row * 4) & 63; // swizzle
                float v = acc[i][j][r] * invn[j];
                v = fminf(fmaxf(v, -(1.0f - EPSF)), 1.0f - EPSF) * SCALE;
                Ew[row * 64 + cs] = v;
            }
#pragma unroll
        for (int rep = 0; rep < 4; ++rep) {
            const int row = rep * 4 + rr;                       // 0..15
            const f32x4 v = *(const f32x4*)&Ew[row * 64 + ((cc + row) & 15) * 4];
            const int grow = m0 + wm * 128 + i * 16 + row;
            const int gcol = n0 + wn * 64 + cc * 4;
            if (gcol < CN)                                      // CN%4==0: all-or-nothing
                *(f32x4*)&out[(size_t)grow * CN + gcol] = v;
        }
    }
}

// Label-column fixup: arccos margin path on exactly B_ROWS elements
__global__ void fixup(const float* __restrict__ norms, const int* __restrict__ label,
                      float* __restrict__ out) {
    const int b = blockIdx.x * 256 + threadIdx.x;
    if (b >= B_ROWS) return;
    const int c = label[b];
    const float safe = fminf(fmaxf(norms[b], 1e-3f), 100.0f);
    const float ms = fminf(fmaxf(safe / (100.0f + 1e-3f) * 0.333f, -1.0f), 1.0f);
    const size_t idx = (size_t)b * CN + c;
    const float cosv = out[idx] * (1.0f / SCALE);        // recover clipped cosine
    float theta = acosf(cosv) + 0.5f * ms;               // + M*ms at label
    theta = fminf(fmaxf(theta, EPSF), 3.14159265358979f - EPSF);
    out[idx] = (cosf(theta) - (0.5f - 0.5f * ms)) * SCALE;  // - (HEAD_B - M*ms), * S
}

extern "C" void kernel_launch(void* const* d_in, const int* in_sizes, int n_in,
                              void* d_out, int out_size, void* d_ws, size_t ws_size,
                              hipStream_t stream) {
    const float* emb   = (const float*)d_in[0];
    const float* norms = (const float*)d_in[1];
    const float* kern  = (const float*)d_in[2];
    const int*   label = (const int*)d_in[3];
    float* out = (float*)d_out;

    char* ws = (char*)d_ws;
    ushort_t* kbT = (ushort_t*)ws;                           // CPAD*DDIM*2 = 52,690,944 B
    size_t off = (size_t)CPAD * DDIM * 2;
    ushort_t* embb = (ushort_t*)(ws + off); off += (size_t)B_ROWS * DDIM * 2;
    float* inv_norm = (float*)(ws + off);   off += (size_t)CPAD * 4;
    float* partials = (float*)(ws + off);   // 8*CPAD*4 B ; total ~55.6 MB

    colpass<<<dim3((CPAD / 2 + 255) / 256, 8), 256, 0, stream>>>(kern, kbT, partials);
    embcast<<<dim3((B_ROWS * DDIM / 4) / 256), 256, 0, stream>>>(emb, embb);
    finnorm<<<dim3(CPAD / 256), 256, 0, stream>>>(partials, inv_norm);
    gemm_kernel<<<dim3(804), 512, 0, stream>>>(embb, kbT, inv_norm, out);
    fixup<<<dim3(B_ROWS / 256), 256, 0, stream>>>(norms, label, out);
}